// Round 13
// baseline (384.457 us; speedup 1.0000x reference)
//
#include <hip/hip_runtime.h>
#include <hip/hip_bf16.h>
#include <hip/hip_fp16.h>

#define DIN 512
#define DOUT 64

typedef float f32x4 __attribute__((ext_vector_type(4)));
typedef _Float16 f16x8 __attribute__((ext_vector_type(8)));
typedef unsigned int uint4v __attribute__((ext_vector_type(4)));
typedef int int4v __attribute__((ext_vector_type(4)));

static __device__ __forceinline__ unsigned int pk_f16(float a, float b) {
  return __builtin_bit_cast(unsigned int, __builtin_amdgcn_cvt_pkrtz(a, b));
}

// decode the 15-bit (sign-dropped) f16 val from a packed edge record
static __device__ __forceinline__ float rec_val(unsigned int rec) {
  const __half h = __ushort_as_half((unsigned short)(rec >> 17));
  return __half2float(h);
}

// ---------------------------------------------------------------------------
// Kernel 0: pre-pack W (f32 [512][64]) -> pw (u32 [64][256]):
//   pw[c][p] = {f16(W[2p][c]), f16(W[2p+1][c])}  (transposed, k-pairs packed)
// ---------------------------------------------------------------------------
__global__ __launch_bounds__(256) void pack_w_kernel(
    const float* __restrict__ W, unsigned int* __restrict__ pw)
{
  const int idx = blockIdx.x * 256 + threadIdx.x;   // 0..16383
  const int c = idx >> 8;
  const int p = idx & 255;
  pw[idx] = pk_f16(W[(size_t)(2 * p) * DOUT + c],
                   W[(size_t)(2 * p + 1) * DOUT + c]);
}

// ---------------------------------------------------------------------------
// Kernel 1: support = leaky_relu(X @ W, 0.2) via f16 MFMA (16x16x32).
// [unchanged from round 6/9/11/12 — passed]
// ---------------------------------------------------------------------------
__global__ __launch_bounds__(256) void gemm_mfma_kernel(
    const float* __restrict__ X, const unsigned int* __restrict__ pw,
    float* __restrict__ sup, int N)
{
  __shared__ unsigned int wlds[64][132];   // cols x k-pairs(half), 33.8 KB

  const int t    = threadIdx.x;
  const int wv   = t >> 6;
  const int lane = t & 63;
  const int l15  = lane & 15;
  const int g    = lane >> 4;

  const int rb   = blockIdx.x * 64 + wv * 16;
  const int rA   = rb + l15;
  const int rowA = rA < N ? rA : N - 1;                 // clamp loads
  const float* __restrict__ xrow = X + (size_t)rowA * DIN;

  const int sc = t >> 2;
  const int sq = t & 3;

  f32x4 acc[4];
#pragma unroll
  for (int f = 0; f < 4; ++f) acc[f] = (f32x4)0.0f;

#pragma unroll 1
  for (int kh = 0; kh < 2; ++kh) {
    const int kbase = kh * 256;

    // ---- issue ALL A loads for this K-half (16 dwordx4 in flight) ----
    f32x4 a[16];
#pragma unroll
    for (int s = 0; s < 8; ++s) {
      a[2 * s]     = *reinterpret_cast<const f32x4*>(xrow + kbase + s * 32 + g * 8);
      a[2 * s + 1] = *reinterpret_cast<const f32x4*>(xrow + kbase + s * 32 + g * 8 + 4);
    }

    // ---- stage W half: contiguous 16B copies ----
    __syncthreads();
    {
      const unsigned int* __restrict__ src = pw + sc * 256 + kh * 128 + sq * 32;
      uint4v* __restrict__ dst = reinterpret_cast<uint4v*>(&wlds[sc][sq * 32]);
#pragma unroll
      for (int i = 0; i < 8; ++i)
        dst[i] = *(reinterpret_cast<const uint4v*>(src) + i);
    }
    __syncthreads();

    // ---- compute ----
#pragma unroll
    for (int s = 0; s < 8; ++s) {
      uint4v au;
      au[0] = pk_f16(a[2 * s][0], a[2 * s][1]);
      au[1] = pk_f16(a[2 * s][2], a[2 * s][3]);
      au[2] = pk_f16(a[2 * s + 1][0], a[2 * s + 1][1]);
      au[3] = pk_f16(a[2 * s + 1][2], a[2 * s + 1][3]);
      const f16x8 afrag = __builtin_bit_cast(f16x8, au);

      const int pb = s * 16 + g * 4;
#pragma unroll
      for (int f = 0; f < 4; ++f) {
        const int c = f * 16 + l15;
        const uint4v bu = *reinterpret_cast<const uint4v*>(&wlds[c][pb]);
        const f16x8 bfrag = __builtin_bit_cast(f16x8, bu);
        acc[f] = __builtin_amdgcn_mfma_f32_16x16x32_f16(afrag, bfrag, acc[f], 0, 0, 0);
      }
    }
  }

  const int r0 = rb + g * 4;
#pragma unroll
  for (int f = 0; f < 4; ++f) {
    const int c = f * 16 + l15;
#pragma unroll
    for (int reg = 0; reg < 4; ++reg) {
      const int r = r0 + reg;
      if (r < N) {
        const float v = acc[f][reg];
        sup[(size_t)r * DOUT + c] = v > 0.0f ? v : 0.2f * v;
      }
    }
  }
}

// ---------------------------------------------------------------------------
// CSR build: histogram -> exclusive scan (3 kernels) -> packed-4B scatter
// ---------------------------------------------------------------------------
__global__ __launch_bounds__(256) void hist_kernel(
    const int* __restrict__ er, int* __restrict__ cnt, int E)
{
  int i = blockIdx.x * blockDim.x + threadIdx.x;
  const int stride = gridDim.x * blockDim.x;
  for (; i < E; i += stride) atomicAdd(&cnt[er[i]], 1);
}

__global__ __launch_bounds__(256) void scan_block_kernel(
    const int* __restrict__ in, int* __restrict__ out,
    int* __restrict__ bsum, int n)
{
  __shared__ int s[256];
  const int t = threadIdx.x;
  const int gid = blockIdx.x * 256 + t;
  const int v = gid < n ? in[gid] : 0;
  s[t] = v;
  __syncthreads();
#pragma unroll
  for (int off = 1; off < 256; off <<= 1) {
    const int add = t >= off ? s[t - off] : 0;
    __syncthreads();
    s[t] += add;
    __syncthreads();
  }
  if (gid < n) out[gid] = s[t] - v;
  if (t == 255) bsum[blockIdx.x] = s[255];
}

__global__ __launch_bounds__(256) void scan_bsums_kernel(int* __restrict__ bsum, int nb)
{
  __shared__ int s[256];
  __shared__ int carry_s;
  const int t = threadIdx.x;
  if (t == 0) carry_s = 0;
  __syncthreads();
  for (int base = 0; base < nb; base += 256) {
    const int i = base + t;
    const int v = i < nb ? bsum[i] : 0;
    s[t] = v;
    __syncthreads();
#pragma unroll
    for (int off = 1; off < 256; off <<= 1) {
      const int add = t >= off ? s[t - off] : 0;
      __syncthreads();
      s[t] += add;
      __syncthreads();
    }
    const int carry = carry_s;
    if (i < nb) bsum[i] = s[t] - v + carry;
    const int total = s[255];
    __syncthreads();
    if (t == 0) carry_s = carry + total;
    __syncthreads();
  }
}

__global__ __launch_bounds__(256) void scan_add_kernel(
    int* __restrict__ out, const int* __restrict__ bsum, int n)
{
  const int gid = blockIdx.x * 256 + threadIdx.x;
  if (gid < n) out[gid] += bsum[blockIdx.x];
}

// packed-4B scatter, 4 edges per thread:
//  - er/ec/ev read as one dwordx4 each (16B/lane, ideal coalescing)
//  - 4 INDEPENDENT atomicAdds issued back-to-back (4x atomic MLP; round-12
//    showed the bottleneck is the serial atomic->store latency chain, not BW)
//  - exact grid: one batch per thread, no grid-stride re-serialization
__global__ __launch_bounds__(256) void scatter_kernel(
    const int* __restrict__ er, const int* __restrict__ ec,
    const float* __restrict__ ev, int* __restrict__ cursor,
    unsigned int* __restrict__ scv, int E)
{
  const int base = (blockIdx.x * 256 + threadIdx.x) * 4;
  if (base + 4 <= E) {
    const int4v r4 = *reinterpret_cast<const int4v*>(er + base);
    const int4v c4 = *reinterpret_cast<const int4v*>(ec + base);
    const f32x4 v4 = *reinterpret_cast<const f32x4*>(ev + base);

    unsigned int rec[4];
#pragma unroll
    for (int j = 0; j < 4; ++j) {
      const unsigned short hb =
          __half_as_ushort(__float2half(v4[j])) & 0x7FFFu;
      rec[j] = ((unsigned int)c4[j] & 0x1FFFFu) | ((unsigned int)hb << 17);
    }

    int pos[4];
#pragma unroll
    for (int j = 0; j < 4; ++j) pos[j] = atomicAdd(&cursor[r4[j]], 1);
#pragma unroll
    for (int j = 0; j < 4; ++j) scv[pos[j]] = rec[j];
  } else {
    for (int i = base; i < E; ++i) {
      const unsigned short hb =
          __half_as_ushort(__float2half(ev[i])) & 0x7FFFu;
      const unsigned int rec =
          ((unsigned int)ec[i] & 0x1FFFFu) | ((unsigned int)hb << 17);
      const int pos = atomicAdd(&cursor[er[i]], 1);
      scv[pos] = rec;
    }
  }
}

// ---------------------------------------------------------------------------
// CSR SpMM: one wave per row, lane = output dim; packed 4B edge records
// (sorted copy -> sequential reads; decode is 2 VALU ops/edge).
// [unchanged from round 12 — passed]
// ---------------------------------------------------------------------------
__global__ __launch_bounds__(256) void spmm_csr_kernel(
    const int* __restrict__ rowptr, const unsigned int* __restrict__ scv,
    const float* __restrict__ x, float* __restrict__ out, int N)
{
  const int lane = threadIdx.x & 63;
  const int row  = blockIdx.x * 4 + (threadIdx.x >> 6);
  if (row >= N) return;

  const int s = rowptr[row];
  const int e = rowptr[row + 1];
  float acc = 0.0f;

  int i = s;
  for (; i + 8 <= e; i += 8) {
    const int b = __builtin_amdgcn_readfirstlane(i);
    unsigned int rr[8];
#pragma unroll
    for (int j = 0; j < 8; ++j) rr[j] = scv[b + j];
    float xx[8];
#pragma unroll
    for (int j = 0; j < 8; ++j)
      xx[j] = x[(size_t)(rr[j] & 0x1FFFFu) * DOUT + lane];
#pragma unroll
    for (int j = 0; j < 8; ++j)
      acc = fmaf(rec_val(rr[j]), xx[j], acc);
  }
  for (; i < e; ++i) {
    const int b = __builtin_amdgcn_readfirstlane(i);
    const unsigned int rec = scv[b];
    acc = fmaf(rec_val(rec), x[(size_t)(rec & 0x1FFFFu) * DOUT + lane], acc);
  }

  out[(size_t)row * DOUT + lane] = acc;
}

// ---------------------------------------------------------------------------
// Launch. ws layout:
//   sup    : N*64 f32          (25.6 MB)
//   rowptr : N+1 int
//   cursor : N+1 int
//   bsum   : 1024 int
//   scv    : E u32             (6.4 MB, packed {f16val,col})
//   pw     : 64*256 u32        (64 KB, packed f16 W)
// ---------------------------------------------------------------------------
extern "C" void kernel_launch(void* const* d_in, const int* in_sizes, int n_in,
                              void* d_out, int out_size, void* d_ws, size_t ws_size,
                              hipStream_t stream)
{
  const float* X  = (const float*)d_in[0];
  const float* W  = (const float*)d_in[1];
  const int*   er = (const int*)d_in[2];
  const int*   ec = (const int*)d_in[3];
  const float* ev = (const float*)d_in[4];

  const int N = in_sizes[0] / DIN;
  const int E = in_sizes[2];
  const size_t half = (size_t)N * DOUT;

  char* w = (char*)d_ws;
  float* sup    = (float*)w;                 w += half * sizeof(float);
  int*   rowptr = (int*)w;                   w += (size_t)(N + 1) * sizeof(int);
  int*   cursor = (int*)w;                   w += (size_t)(N + 1) * sizeof(int);
  int*   bsum   = (int*)w;                   w += 1024 * sizeof(int);
  unsigned int* scv = (unsigned int*)w;      w += (size_t)E * sizeof(unsigned int);
  unsigned int* pw  = (unsigned int*)w;

  float* out0 = (float*)d_out;
  float* out1 = out0 + half;

  const int n_scan = N + 1;
  const int nb = (n_scan + 255) / 256;

  // ---- CSR build ----
  (void)hipMemsetAsync(cursor, 0, (size_t)n_scan * sizeof(int), stream);
  hist_kernel<<<2048, 256, 0, stream>>>(er, cursor, E);
  scan_block_kernel<<<nb, 256, 0, stream>>>(cursor, rowptr, bsum, n_scan);
  scan_bsums_kernel<<<1, 256, 0, stream>>>(bsum, nb);
  scan_add_kernel<<<nb, 256, 0, stream>>>(rowptr, bsum, n_scan);
  (void)hipMemcpyAsync(cursor, rowptr, (size_t)n_scan * sizeof(int),
                       hipMemcpyDeviceToDevice, stream);
  const int nb_scatter = (E / 4 + 255) / 256;   // 4 edges per thread
  scatter_kernel<<<nb_scatter, 256, 0, stream>>>(er, ec, ev, cursor, scv, E);

  // ---- W pre-pack + support = leaky_relu(X @ W) via MFMA ----
  pack_w_kernel<<<64, 256, 0, stream>>>(W, pw);
  gemm_mfma_kernel<<<(N + 63) / 64, 256, 0, stream>>>(X, pw, sup, N);

  // ---- output = A @ support ; az = A @ output ----
  spmm_csr_kernel<<<(N + 3) / 4, 256, 0, stream>>>(rowptr, scv, sup, out0, N);
  spmm_csr_kernel<<<(N + 3) / 4, 256, 0, stream>>>(rowptr, scv, out0, out1, N);
}

// Round 14
// 366.406 us; speedup vs baseline: 1.0493x; 1.0493x over previous
//
#include <hip/hip_runtime.h>
#include <hip/hip_bf16.h>
#include <hip/hip_fp16.h>

#define DIN 512
#define DOUT 64
#define SCB 2048   // scatter blocks inside the fat kernel

typedef float f32x4 __attribute__((ext_vector_type(4)));
typedef _Float16 f16x8 __attribute__((ext_vector_type(8)));
typedef unsigned int uint4v __attribute__((ext_vector_type(4)));

static __device__ __forceinline__ unsigned int pk_f16(float a, float b) {
  return __builtin_bit_cast(unsigned int, __builtin_amdgcn_cvt_pkrtz(a, b));
}

// decode the 15-bit (sign-dropped) f16 val from a packed edge record
static __device__ __forceinline__ float rec_val(unsigned int rec) {
  const __half h = __ushort_as_half((unsigned short)(rec >> 17));
  return __half2float(h);
}

// ---------------------------------------------------------------------------
// Kernel 0: pre-pack W (f32 [512][64]) -> pw (u32 [64][256])
// ---------------------------------------------------------------------------
__global__ __launch_bounds__(256) void pack_w_kernel(
    const float* __restrict__ W, unsigned int* __restrict__ pw)
{
  const int idx = blockIdx.x * 256 + threadIdx.x;   // 0..16383
  const int c = idx >> 8;
  const int p = idx & 255;
  pw[idx] = pk_f16(W[(size_t)(2 * p) * DOUT + c],
                   W[(size_t)(2 * p + 1) * DOUT + c]);
}

// ---------------------------------------------------------------------------
// FAT kernel: blocks [0,SCB) run the round-12 scatter (grid-stride over E);
// blocks [SCB, SCB+(N+63)/64) run the round-6 MFMA gemm on rows
// (blockIdx-SCB)*64... Scatter is memory-side-RMW bound (0.3% VALU, 11% HBM);
// gemm is HBM-read+MFMA bound — disjoint resources, so overlapping them hides
// the cheaper one (~50 us of gemm) under the scatter floor (~130 us).
// Block-uniform branch; __syncthreads only in the gemm path (legal).
// ---------------------------------------------------------------------------
__global__ __launch_bounds__(256) void fat_scatter_gemm_kernel(
    // scatter args
    const int* __restrict__ er, const int* __restrict__ ec,
    const float* __restrict__ ev, int* __restrict__ cursor,
    unsigned int* __restrict__ scv, int E,
    // gemm args
    const float* __restrict__ X, const unsigned int* __restrict__ pw,
    float* __restrict__ sup, int N)
{
  __shared__ unsigned int wlds[64][132];   // used by gemm path only (33.8 KB)

  if (blockIdx.x < SCB) {
    // ================= scatter path (round-12 body, verbatim) =============
    int i = blockIdx.x * 256 + threadIdx.x;
    const int stride = SCB * 256;
    for (; i < E; i += stride) {
      const int r = er[i];
      const unsigned short hb =
          __half_as_ushort(__float2half(ev[i])) & 0x7FFFu;   // RNE, sign=0
      const unsigned int rec =
          ((unsigned int)ec[i] & 0x1FFFFu) | ((unsigned int)hb << 17);
      const int pos = atomicAdd(&cursor[r], 1);
      scv[pos] = rec;
    }
    return;
  }

  // ================= gemm path (round-6 body, rebased blockIdx) ===========
  const int blk  = blockIdx.x - SCB;
  const int t    = threadIdx.x;
  const int wv   = t >> 6;
  const int lane = t & 63;
  const int l15  = lane & 15;
  const int g    = lane >> 4;

  const int rb   = blk * 64 + wv * 16;
  const int rA   = rb + l15;
  const int rowA = rA < N ? rA : N - 1;                 // clamp loads
  const float* __restrict__ xrow = X + (size_t)rowA * DIN;

  const int sc = t >> 2;
  const int sq = t & 3;

  f32x4 acc[4];
#pragma unroll
  for (int f = 0; f < 4; ++f) acc[f] = (f32x4)0.0f;

#pragma unroll 1
  for (int kh = 0; kh < 2; ++kh) {
    const int kbase = kh * 256;

    // ---- issue ALL A loads for this K-half (16 dwordx4 in flight) ----
    f32x4 a[16];
#pragma unroll
    for (int s = 0; s < 8; ++s) {
      a[2 * s]     = *reinterpret_cast<const f32x4*>(xrow + kbase + s * 32 + g * 8);
      a[2 * s + 1] = *reinterpret_cast<const f32x4*>(xrow + kbase + s * 32 + g * 8 + 4);
    }

    // ---- stage W half: contiguous 16B copies ----
    __syncthreads();
    {
      const unsigned int* __restrict__ src = pw + sc * 256 + kh * 128 + sq * 32;
      uint4v* __restrict__ dst = reinterpret_cast<uint4v*>(&wlds[sc][sq * 32]);
#pragma unroll
      for (int i = 0; i < 8; ++i)
        dst[i] = *(reinterpret_cast<const uint4v*>(src) + i);
    }
    __syncthreads();

    // ---- compute ----
#pragma unroll
    for (int s = 0; s < 8; ++s) {
      uint4v au;
      au[0] = pk_f16(a[2 * s][0], a[2 * s][1]);
      au[1] = pk_f16(a[2 * s][2], a[2 * s][3]);
      au[2] = pk_f16(a[2 * s + 1][0], a[2 * s + 1][1]);
      au[3] = pk_f16(a[2 * s + 1][2], a[2 * s + 1][3]);
      const f16x8 afrag = __builtin_bit_cast(f16x8, au);

      const int pb = s * 16 + g * 4;
#pragma unroll
      for (int f = 0; f < 4; ++f) {
        const int c = f * 16 + l15;
        const uint4v bu = *reinterpret_cast<const uint4v*>(&wlds[c][pb]);
        const f16x8 bfrag = __builtin_bit_cast(f16x8, bu);
        acc[f] = __builtin_amdgcn_mfma_f32_16x16x32_f16(afrag, bfrag, acc[f], 0, 0, 0);
      }
    }
  }

  const int r0 = rb + g * 4;
#pragma unroll
  for (int f = 0; f < 4; ++f) {
    const int c = f * 16 + l15;
#pragma unroll
    for (int reg = 0; reg < 4; ++reg) {
      const int r = r0 + reg;
      if (r < N) {
        const float v = acc[f][reg];
        sup[(size_t)r * DOUT + c] = v > 0.0f ? v : 0.2f * v;
      }
    }
  }
}

// ---------------------------------------------------------------------------
// CSR build: histogram -> exclusive scan (3 kernels)
// ---------------------------------------------------------------------------
__global__ __launch_bounds__(256) void hist_kernel(
    const int* __restrict__ er, int* __restrict__ cnt, int E)
{
  int i = blockIdx.x * blockDim.x + threadIdx.x;
  const int stride = gridDim.x * blockDim.x;
  for (; i < E; i += stride) atomicAdd(&cnt[er[i]], 1);
}

__global__ __launch_bounds__(256) void scan_block_kernel(
    const int* __restrict__ in, int* __restrict__ out,
    int* __restrict__ bsum, int n)
{
  __shared__ int s[256];
  const int t = threadIdx.x;
  const int gid = blockIdx.x * 256 + t;
  const int v = gid < n ? in[gid] : 0;
  s[t] = v;
  __syncthreads();
#pragma unroll
  for (int off = 1; off < 256; off <<= 1) {
    const int add = t >= off ? s[t - off] : 0;
    __syncthreads();
    s[t] += add;
    __syncthreads();
  }
  if (gid < n) out[gid] = s[t] - v;
  if (t == 255) bsum[blockIdx.x] = s[255];
}

__global__ __launch_bounds__(256) void scan_bsums_kernel(int* __restrict__ bsum, int nb)
{
  __shared__ int s[256];
  __shared__ int carry_s;
  const int t = threadIdx.x;
  if (t == 0) carry_s = 0;
  __syncthreads();
  for (int base = 0; base < nb; base += 256) {
    const int i = base + t;
    const int v = i < nb ? bsum[i] : 0;
    s[t] = v;
    __syncthreads();
#pragma unroll
    for (int off = 1; off < 256; off <<= 1) {
      const int add = t >= off ? s[t - off] : 0;
      __syncthreads();
      s[t] += add;
      __syncthreads();
    }
    const int carry = carry_s;
    if (i < nb) bsum[i] = s[t] - v + carry;
    const int total = s[255];
    __syncthreads();
    if (t == 0) carry_s = carry + total;
    __syncthreads();
  }
}

__global__ __launch_bounds__(256) void scan_add_kernel(
    int* __restrict__ out, const int* __restrict__ bsum, int n)
{
  const int gid = blockIdx.x * 256 + threadIdx.x;
  if (gid < n) out[gid] += bsum[blockIdx.x];
}

// ---------------------------------------------------------------------------
// CSR SpMM: one wave per row, lane = output dim; packed 4B edge records.
// [unchanged from round 12 — passed]
// ---------------------------------------------------------------------------
__global__ __launch_bounds__(256) void spmm_csr_kernel(
    const int* __restrict__ rowptr, const unsigned int* __restrict__ scv,
    const float* __restrict__ x, float* __restrict__ out, int N)
{
  const int lane = threadIdx.x & 63;
  const int row  = blockIdx.x * 4 + (threadIdx.x >> 6);
  if (row >= N) return;

  const int s = rowptr[row];
  const int e = rowptr[row + 1];
  float acc = 0.0f;

  int i = s;
  for (; i + 8 <= e; i += 8) {
    const int b = __builtin_amdgcn_readfirstlane(i);
    unsigned int rr[8];
#pragma unroll
    for (int j = 0; j < 8; ++j) rr[j] = scv[b + j];
    float xx[8];
#pragma unroll
    for (int j = 0; j < 8; ++j)
      xx[j] = x[(size_t)(rr[j] & 0x1FFFFu) * DOUT + lane];
#pragma unroll
    for (int j = 0; j < 8; ++j)
      acc = fmaf(rec_val(rr[j]), xx[j], acc);
  }
  for (; i < e; ++i) {
    const int b = __builtin_amdgcn_readfirstlane(i);
    const unsigned int rec = scv[b];
    acc = fmaf(rec_val(rec), x[(size_t)(rec & 0x1FFFFu) * DOUT + lane], acc);
  }

  out[(size_t)row * DOUT + lane] = acc;
}

// ---------------------------------------------------------------------------
// Launch. ws layout:
//   sup    : N*64 f32          (25.6 MB)
//   rowptr : N+1 int
//   cursor : N+1 int
//   bsum   : 1024 int
//   scv    : E u32             (6.4 MB, packed {f16val,col})
//   pw     : 64*256 u32        (64 KB, packed f16 W)
// ---------------------------------------------------------------------------
extern "C" void kernel_launch(void* const* d_in, const int* in_sizes, int n_in,
                              void* d_out, int out_size, void* d_ws, size_t ws_size,
                              hipStream_t stream)
{
  const float* X  = (const float*)d_in[0];
  const float* W  = (const float*)d_in[1];
  const int*   er = (const int*)d_in[2];
  const int*   ec = (const int*)d_in[3];
  const float* ev = (const float*)d_in[4];

  const int N = in_sizes[0] / DIN;
  const int E = in_sizes[2];
  const size_t half = (size_t)N * DOUT;

  char* w = (char*)d_ws;
  float* sup    = (float*)w;                 w += half * sizeof(float);
  int*   rowptr = (int*)w;                   w += (size_t)(N + 1) * sizeof(int);
  int*   cursor = (int*)w;                   w += (size_t)(N + 1) * sizeof(int);
  int*   bsum   = (int*)w;                   w += 1024 * sizeof(int);
  unsigned int* scv = (unsigned int*)w;      w += (size_t)E * sizeof(unsigned int);
  unsigned int* pw  = (unsigned int*)w;

  float* out0 = (float*)d_out;
  float* out1 = out0 + half;

  const int n_scan = N + 1;
  const int nb = (n_scan + 255) / 256;

  // ---- CSR counts + rowptr ----
  (void)hipMemsetAsync(cursor, 0, (size_t)n_scan * sizeof(int), stream);
  hist_kernel<<<2048, 256, 0, stream>>>(er, cursor, E);
  scan_block_kernel<<<nb, 256, 0, stream>>>(cursor, rowptr, bsum, n_scan);
  scan_bsums_kernel<<<1, 256, 0, stream>>>(bsum, nb);
  scan_add_kernel<<<nb, 256, 0, stream>>>(rowptr, bsum, n_scan);
  (void)hipMemcpyAsync(cursor, rowptr, (size_t)n_scan * sizeof(int),
                       hipMemcpyDeviceToDevice, stream);

  // ---- W pre-pack (gemm input) ----
  pack_w_kernel<<<64, 256, 0, stream>>>(W, pw);

  // ---- FUSED: scatter (blocks 0..SCB) || gemm (remaining blocks) ----
  const int gemm_blocks = (N + 63) / 64;
  fat_scatter_gemm_kernel<<<SCB + gemm_blocks, 256, 0, stream>>>(
      er, ec, ev, cursor, scv, E, X, pw, sup, N);

  // ---- output = A @ support ; az = A @ output ----
  spmm_csr_kernel<<<(N + 3) / 4, 256, 0, stream>>>(rowptr, scv, sup, out0, N);
  spmm_csr_kernel<<<(N + 3) / 4, 256, 0, stream>>>(rowptr, scv, out0, out1, N);
}